// Round 5
// baseline (373.418 us; speedup 1.0000x reference)
//
#include <hip/hip_runtime.h>
#include <hip/hip_bf16.h>
#include <stdint.h>

// Problem constants
#define NATOMS 32768
#define DDIM   1024
#define HDIM   1024
#define ENUM   4
// Expert segments padded to 256 (superset of the 128 alignment the 128-row
// tiles need). Worst-case padded M <= 33536; cap 33792 for slack.
#define MCAP   33792

typedef unsigned short u16;
typedef unsigned char  u8;
typedef __attribute__((ext_vector_type(8)))  int   i32x8;
typedef __attribute__((ext_vector_type(16))) float f32x16;

// ---- workspace layout (bytes) ----
static const size_t XP_OFF   = 0;
static const size_t H1_OFF   = XP_OFF  + (size_t)MCAP * 1024;
static const size_t W1T_OFF  = H1_OFF  + (size_t)MCAP * 1024;
static const size_t W2T_OFF  = W1T_OFF + (size_t)ENUM * 1024 * 1024;
static const size_t PERM_OFF = W2T_OFF + (size_t)ENUM * 1024 * 1024;
static const size_t META_OFF = PERM_OFF + (size_t)MCAP * 4;
// meta ints: count[e] at e*16; offs[0..3] at 128..131; Mpad at 132

__device__ __forceinline__ u8 f2fp8(float x) {
    int w = __builtin_amdgcn_cvt_pk_fp8_f32(x, x, 0, false);
    return (u8)(w & 0xFF);
}

// ------- R13: count + offsets + scatter + pad-init fused, single block -------
// One 1024-thread block reads sym twice (256 KB, L2): phase 1 wave-aggregated
// histogram, phase 2 offsets/constant-term, phase 3 wave-aggregated scatter
// with LDS cursors, phase 4 pad perm slots -> 0. Replaces 3 kernel launches.
__global__ __launch_bounds__(1024)
void k_prep(const int* __restrict__ sym, int* __restrict__ meta,
            int* __restrict__ perm, const float* __restrict__ slope,
            const float* __restrict__ b3, const float* __restrict__ inter,
            float* __restrict__ out) {
    __shared__ int cnt[4], cur[4], offw[4], padE[4];
    int t = threadIdx.x, lane = t & 63;
    if (t < 4) cnt[t] = 0;
    __syncthreads();
    for (int base = 0; base < NATOMS; base += 1024) {
        int e = sym[base + t];
#pragma unroll
        for (int j = 0; j < ENUM; ++j) {
            unsigned long long mask = __ballot(e == j);
            if (mask && lane == __ffsll((long long)mask) - 1)
                atomicAdd(&cnt[j], __popcll(mask));
        }
    }
    __syncthreads();
    if (t == 0) {
        int off = 0;
        float c = 0.f;
        for (int e = 0; e < 4; ++e) {
            int cc = cnt[e];
            meta[e * 16]  = cc;            // total count
            meta[128 + e] = off;           // segment start
            offw[e] = off;
            cur[e]  = off;                 // scatter cursor
            c += (float)cc * (slope[e] * b3[e] + inter[e]);
            off += (cc + 255) & ~255;
            padE[e] = off;
        }
        meta[132] = off;                   // Mpad
        out[0] = c;                        // per-atom constant terms, summed
    }
    __syncthreads();
    for (int base = 0; base < NATOMS; base += 1024) {
        int n = base + t;
        int e = sym[n];
#pragma unroll
        for (int j = 0; j < ENUM; ++j) {
            unsigned long long mask = __ballot(e == j);
            if (mask) {
                int leader = __ffsll((long long)mask) - 1;
                int b = 0;
                if (lane == leader) b = atomicAdd(&cur[j], __popcll(mask));
                b = __shfl(b, leader, 64);
                if (e == j) {
                    int rank = __popcll(mask & ((1ull << lane) - 1ull));
                    perm[b + rank] = n;
                }
            }
        }
    }
    __syncthreads();
    // pad perm slots -> row 0 (gemm1's permuted staging reads valid memory;
    // garbage h1 rows masked by segEnd in the FUSE epilogue)
#pragma unroll
    for (int e = 0; e < 4; ++e) {
        int ps = offw[e] + cnt[e];
        for (int i = ps + t; i < padE[e]; i += 1024) perm[i] = 0;
    }
}

// -------- features fp32 -> fp8, STREAMING (permutation lives in gemm1's
// -------- per-lane global_load_lds source addresses) --------
__global__ void k_conv8(const float* __restrict__ F, u8* __restrict__ X8) {
    int g = blockIdx.x * 256 + threadIdx.x;    // chunk of 8 elements
    const float* fp = F + (size_t)g * 8;
    int w0 = 0, w1 = 0;
    w0 = __builtin_amdgcn_cvt_pk_fp8_f32(fp[0], fp[1], w0, false);
    w0 = __builtin_amdgcn_cvt_pk_fp8_f32(fp[2], fp[3], w0, true);
    w1 = __builtin_amdgcn_cvt_pk_fp8_f32(fp[4], fp[5], w1, false);
    w1 = __builtin_amdgcn_cvt_pk_fp8_f32(fp[6], fp[7], w1, true);
    uint2 v; v.x = (unsigned)w0; v.y = (unsigned)w1;
    *(uint2*)(void*)(X8 + (size_t)g * 8) = v;
}

// -------- W [E][K][N] fp32 -> WT [E][N][K] fp8 of 32*W (z: 0=W1,1=W2) --------
__global__ void k_transw(const float* __restrict__ W1, u8* __restrict__ W1T,
                         const float* __restrict__ W2, u8* __restrict__ W2T) {
    __shared__ u8 tile[64][65];
    const float* W  = blockIdx.z ? W2  : W1;
    u8*          WT = blockIdx.z ? W2T : W1T;
    int e  = blockIdx.y;
    int tn = blockIdx.x & 15;
    int tk = blockIdx.x >> 4;
    const float* Wp = W  + (size_t)e * 1024 * 1024;
    u8*         WTp = WT + (size_t)e * 1024 * 1024;
    int c = threadIdx.x & 63, r0 = threadIdx.x >> 6;
#pragma unroll
    for (int i = 0; i < 16; ++i) {
        int r = r0 + i * 4;
        tile[r][c] = f2fp8(32.0f * Wp[(size_t)(tk * 64 + r) * 1024 + tn * 64 + c]);
    }
    __syncthreads();
#pragma unroll
    for (int i = 0; i < 16; ++i) {
        int r = r0 + i * 4;
        WTp[(size_t)(tn * 64 + r) * 1024 + tk * 64 + c] = tile[c][r];
    }
}

// ---------------- MX-fp8 MFMA GEMM: relu(A * (32B)^T * 2^-5 + bias) ----------------
// R13: 128x128 tile, 4 waves of 64x64 (acc[2][2]=64 regs, zero spill risk),
// DOUBLE-BUFFERED 64 KiB LDS -> 2 blocks/CU, with the R9-proven sync pattern:
//   BAR -> STAGE(next tile, 8 loads) -> vmcnt(8) -> BAR -> compute
// Next-tile loads fly under the ~1100cy compute phase, so the steady-state
// vmcnt(8) wait is ~0 -- this removes the per-K-tile __syncthreads vmcnt(0)
// drain that capped R7/R11/R12 at ~24% MfmaUtil (2202cy MFMA + 2304cy LDS
// per CU per K-tile-pair should bound at ~16us/gemm; we measured 62).
// R9 failed at 1 block/CU (256^2, no TLP to cover sync); R10 failed via
// spills from per-phase barriers. Here: 2 blocks/CU, monolithic compute,
// no barriers inside compute, no fragment state live across barriers.
// LDS swizzle (R12): 16B chunk c of row r holds global chunk c^(r&7)^((r>>3)&3)
// -> conflict-free ds_read_b128 (R12: SQ_LDS_BANK_CONFLICT 3.19M -> ~0).
// PERM: gemm1 stages A rows via per-lane PERMUTED global source addresses
// (global_load_lds global source is per-lane, LDS dest linear -- m173).
// XCD swizzle (R0-proven): mt=(flat>>6)*8+(flat&7), nt=(flat&63)>>3.
template <bool FUSE, bool PERM>
__global__ __launch_bounds__(256, 2)
void k_gemm(const u8* __restrict__ A, const u8* __restrict__ BT,
            const float* __restrict__ bias, u8* __restrict__ C,
            const int* __restrict__ meta, const float* __restrict__ W3,
            const float* __restrict__ slope, float* __restrict__ out,
            const int* __restrict__ perm) {
    __shared__ u8 As[2][128 * 128];   // 32 KB
    __shared__ u8 Bs[2][128 * 128];   // 32 KB
    const int* offs = meta + 128;

    // grid = dim3(8, 264) -> flat 0..2111
    const int flat = blockIdx.y * 8 + blockIdx.x;
    const int mt = (flat >> 6) * 8 + (flat & 7);   // m tile (0..263)
    const int nt = (flat & 63) >> 3;               // n tile (0..7)
    const int m0 = mt * 128, n0 = nt * 128;
    if (m0 >= meta[132]) return;                   // beyond actual padded M
    const int e = (m0 >= offs[1]) + (m0 >= offs[2]) + (m0 >= offs[3]);

    const int t = threadIdx.x;                 // 0..255
    const int w = t >> 6, lane = t & 63;
    const int l31 = lane & 31, khalf = lane >> 5;
    const int wm = w & 1, wn = w >> 1;         // 2x2 waves, each 64x64

    const u8* Bg = BT + (size_t)e * 1024 * 1024 + (size_t)n0 * 1024;

    // staging: instr i covers rows i*32+(t>>3), 16B chunk t&7; source chunk
    // pre-swizzled (t&7)^(r&7)^((r>>3)&3); LDS dest linear.
    const int srow = t >> 3;                   // 0..31
    const int gcol = (((t & 7) ^ (srow & 7) ^ ((srow >> 3) & 3)) * 16);

    const u8* arow[4];
#pragma unroll
    for (int i = 0; i < 4; ++i) {
        int r = i * 32 + srow;
        size_t src = PERM ? (size_t)perm[m0 + r] : (size_t)(m0 + r);
        arow[i] = A + src * 1024 + gcol;
    }
    const u8* brow[4];
#pragma unroll
    for (int i = 0; i < 4; ++i)
        brow[i] = Bg + (size_t)(i * 32 + srow) * 1024 + gcol;

    f32x16 acc[2][2] = {};

#define SSTAGE(buf, ktile)                                                      \
    do {                                                                        \
        const size_t kb_ = (size_t)(ktile) * 128;                               \
        _Pragma("unroll")                                                       \
        for (int i = 0; i < 4; ++i)                                             \
            __builtin_amdgcn_global_load_lds((const void*)(arow[i] + kb_),      \
                (void*)(&As[buf][i * 4096 + w * 1024]), 16, 0, 0);              \
        _Pragma("unroll")                                                       \
        for (int i = 0; i < 4; ++i)                                             \
            __builtin_amdgcn_global_load_lds((const void*)(brow[i] + kb_),      \
                (void*)(&Bs[buf][i * 4096 + w * 1024]), 16, 0, 0);              \
    } while (0)
#define FENCE asm volatile("" ::: "memory")
#define BAR   do { FENCE; __builtin_amdgcn_s_barrier(); FENCE; } while (0)

    SSTAGE(0, 0);                              // prologue: tile 0 -> buf 0

#pragma unroll 2
    for (int kt = 0; kt < 8; ++kt) {
        const int cur = kt & 1;
        // B1: all waves finished READING buf[cur^1] (prev iteration's compute)
        BAR;
        if (kt < 7) {
            SSTAGE(cur ^ 1, kt + 1);           // 8 loads fly under compute
            asm volatile("s_waitcnt vmcnt(8)" ::: "memory");  // tile kt landed
        } else {
            asm volatile("s_waitcnt vmcnt(0)" ::: "memory");
        }
        // B2: buf[cur] visible to every wave
        BAR;

        const u8* Ab = &As[cur][0];
        const u8* Bb = &Bs[cur][0];
#pragma unroll
        for (int kk = 0; kk < 2; ++kk) {
            const int c0 = 4 * kk + 2 * khalf;
            i32x8 b[2];
#pragma unroll
            for (int ni = 0; ni < 2; ++ni) {
                int n = wn * 64 + ni * 32 + l31;
                const u8* base = Bb + n * 128;
                int sw = (n & 7) ^ ((n >> 3) & 3);
                int lo = ((c0 ^ sw) << 4);
                union { uint4 q[2]; i32x8 v; } u;
                u.q[0] = *(const uint4*)(const void*)(base + lo);
                u.q[1] = *(const uint4*)(const void*)(base + (lo ^ 16));
                b[ni] = u.v;
            }
#pragma unroll
            for (int mi = 0; mi < 2; ++mi) {
                int m = wm * 64 + mi * 32 + l31;
                const u8* base = Ab + m * 128;
                int sw = (m & 7) ^ ((m >> 3) & 3);
                int lo = ((c0 ^ sw) << 4);
                union { uint4 q[2]; i32x8 v; } u;
                u.q[0] = *(const uint4*)(const void*)(base + lo);
                u.q[1] = *(const uint4*)(const void*)(base + (lo ^ 16));
                i32x8 a = u.v;
#pragma unroll
                for (int ni = 0; ni < 2; ++ni)
                    acc[mi][ni] = __builtin_amdgcn_mfma_scale_f32_32x32x64_f8f6f4(
                        a, b[ni], acc[mi][ni],
                        0, 0,                       // cbsz=fp8(e4m3), blgp=fp8(e4m3)
                        0, 0x7F7F7F7F,              // A scale 2^0
                        0, 0x7A7A7A7A);             // B scale 2^-5 (undo 32*W)
            }
        }
    }
#undef SSTAGE
#undef FENCE
#undef BAR

    // epilogue.  32x32 C/D layout: col=lane&31, row=(reg&3)+8*(reg>>2)+4*(lane>>5)
    if (!FUSE) {
#pragma unroll
        for (int ni = 0; ni < 2; ++ni) {
            int col = n0 + wn * 64 + ni * 32 + l31;
            float bv = bias[e * 1024 + col];
#pragma unroll
            for (int mi = 0; mi < 2; ++mi) {
                int rowb = m0 + wm * 64 + mi * 32 + 4 * khalf;
#pragma unroll
                for (int reg = 0; reg < 16; ++reg) {
                    int rowg = rowb + (reg & 3) + 8 * (reg >> 2);
                    float v = acc[mi][ni][reg] + bv;
                    v = v > 0.f ? v : 0.f;
                    C[(size_t)rowg * 1024 + col] = f2fp8(v);
                }
            }
        }
    } else {
        const int segEnd = offs[e] + meta[e * 16];   // valid slots < segEnd
        const float se = slope[e];
        float psum = 0.f;
#pragma unroll
        for (int ni = 0; ni < 2; ++ni) {
            int col = n0 + wn * 64 + ni * 32 + l31;
            float bv  = bias[e * 1024 + col];
            float w3s = W3[e * 1024 + col] * se;
#pragma unroll
            for (int mi = 0; mi < 2; ++mi) {
                int rowb = m0 + wm * 64 + mi * 32 + 4 * khalf;
#pragma unroll
                for (int reg = 0; reg < 16; ++reg) {
                    int rowg = rowb + (reg & 3) + 8 * (reg >> 2);
                    float v = acc[mi][ni][reg] + bv;
                    v = v > 0.f ? v : 0.f;
                    psum += (rowg < segEnd) ? v * w3s : 0.f;
                }
            }
        }
#pragma unroll
        for (int o = 32; o; o >>= 1) psum += __shfl_xor(psum, o, 64);
        __syncthreads();                 // all waves done reading As/Bs
        float* red = (float*)&As[0][0];
        if (lane == 0) red[w] = psum;
        __syncthreads();
        if (t == 0) atomicAdd(out, red[0] + red[1] + red[2] + red[3]);
    }
}

extern "C" void kernel_launch(void* const* d_in, const int* in_sizes, int n_in,
                              void* d_out, int out_size, void* d_ws, size_t ws_size,
                              hipStream_t stream) {
    const float* features = (const float*)d_in[0];
    const int*   sym      = (const int*)d_in[1];
    const float* W1       = (const float*)d_in[2];
    const float* b1       = (const float*)d_in[3];
    const float* W2       = (const float*)d_in[4];
    const float* b2       = (const float*)d_in[5];
    const float* W3       = (const float*)d_in[6];
    const float* b3       = (const float*)d_in[7];
    const float* slope    = (const float*)d_in[8];
    const float* inter    = (const float*)d_in[9];
    float* out = (float*)d_out;

    char* ws  = (char*)d_ws;
    u8*  X8   = (u8*)(ws + XP_OFF);
    u8*  H1b  = (u8*)(ws + H1_OFF);
    u8*  W1T  = (u8*)(ws + W1T_OFF);
    u8*  W2T  = (u8*)(ws + W2T_OFF);
    int* perm = (int*)(ws + PERM_OFF);
    int* meta = (int*)(ws + META_OFF);

    k_prep<<<1, 1024, 0, stream>>>(sym, meta, perm, slope, b3, inter, out);
    k_conv8<<<(NATOMS * 128) / 256, 256, 0, stream>>>(features, X8);
    k_transw<<<dim3(256, 4, 2), 256, 0, stream>>>(W1, W1T, W2, W2T);
    k_gemm<false, true><<<dim3(8, 264), 256, 0, stream>>>(X8, W1T, b1, H1b, meta,
                                                          nullptr, nullptr, nullptr,
                                                          perm);
    k_gemm<true, false><<<dim3(8, 264), 256, 0, stream>>>(H1b, W2T, b2, nullptr,
                                                          meta, W3, slope, out,
                                                          nullptr);
}

// Round 6
// 346.745 us; speedup vs baseline: 1.0769x; 1.0769x over previous
//
#include <hip/hip_runtime.h>
#include <hip/hip_bf16.h>
#include <stdint.h>

// Problem constants
#define NATOMS 32768
#define DDIM   1024
#define HDIM   1024
#define ENUM   4
// Expert segments padded to 256 so a 256-row GEMM tile never spans two experts.
// Worst-case padded M <= 33536; cap 33792 (132*256) for slack.
#define MCAP   33792

typedef unsigned short u16;
typedef unsigned char  u8;
typedef __attribute__((ext_vector_type(8)))  int   i32x8;
typedef __attribute__((ext_vector_type(16))) float f32x16;

// ---- workspace layout (bytes) ----
static const size_t XP_OFF   = 0;
static const size_t H1_OFF   = XP_OFF  + (size_t)MCAP * 1024;
static const size_t W1T_OFF  = H1_OFF  + (size_t)MCAP * 1024;
static const size_t W2T_OFF  = W1T_OFF + (size_t)ENUM * 1024 * 1024;
static const size_t PERM_OFF = W2T_OFF + (size_t)ENUM * 1024 * 1024;
static const size_t META_OFF = PERM_OFF + (size_t)MCAP * 4;
// meta ints: count[e] at e*16; cursor[e] at 64+e*16; offs[0..3] at 128..131;
// Mpad at 132; per-block count partials at 256 + b*4 + e  (b in [0,128))

__device__ __forceinline__ u8 f2fp8(float x) {
    int w = __builtin_amdgcn_cvt_pk_fp8_f32(x, x, 0, false);
    return (u8)(w & 0xFF);
}

// ---------------- R14 fused bulk-prep: conv8 | transw | count ----------------
// Three INDEPENDENT kernels merged into one launch (blockIdx.x partition):
//   [0, 16384)        : features fp32 -> fp8 streaming (conv8)
//   [16384, 18432)    : W1/W2 [E][K][N] fp32 -> WT [E][N][K] fp8 of 32*W
//   [18432, 18560)    : per-block expert histogram partials (count)
// Same per-block code as the R12-proven standalone kernels; merging removes
// two launch gaps and lets the streaming conversion overlap the transpose.
__global__ __launch_bounds__(256)
void k_fused(const float* __restrict__ F, u8* __restrict__ X8,
             const float* __restrict__ W1, u8* __restrict__ W1T,
             const float* __restrict__ W2, u8* __restrict__ W2T,
             const int* __restrict__ sym, int* __restrict__ meta) {
    __shared__ u8 tile[64][65];        // transw path (also reused as cnt)
    __shared__ int cnt[4];
    const int bx = blockIdx.x;
    const int t  = threadIdx.x;

    if (bx < 16384) {
        // ---- conv8: features fp32 -> fp8, perfectly coalesced ----
        int g = bx * 256 + t;                  // chunk of 8 elements
        const float* fp = F + (size_t)g * 8;
        int w0 = 0, w1 = 0;
        w0 = __builtin_amdgcn_cvt_pk_fp8_f32(fp[0], fp[1], w0, false);
        w0 = __builtin_amdgcn_cvt_pk_fp8_f32(fp[2], fp[3], w0, true);
        w1 = __builtin_amdgcn_cvt_pk_fp8_f32(fp[4], fp[5], w1, false);
        w1 = __builtin_amdgcn_cvt_pk_fp8_f32(fp[6], fp[7], w1, true);
        uint2 v; v.x = (unsigned)w0; v.y = (unsigned)w1;
        *(uint2*)(void*)(X8 + (size_t)g * 8) = v;
    } else if (bx < 18432) {
        // ---- transw: W [E][K][N] -> WT [E][N][K] fp8 of 32*W ----
        int idx = bx - 16384;                  // 0..2047 = 256*4*2
        int z  = idx >> 10;                    // 0=W1, 1=W2
        int e  = (idx >> 8) & 3;
        int tn = idx & 15;
        int tk = (idx & 255) >> 4;
        const float* W  = z ? W2  : W1;
        u8*          WT = z ? W2T : W1T;
        const float* Wp = W  + (size_t)e * 1024 * 1024;
        u8*         WTp = WT + (size_t)e * 1024 * 1024;
        int c = t & 63, r0 = t >> 6;
#pragma unroll
        for (int i = 0; i < 16; ++i) {
            int r = r0 + i * 4;
            tile[r][c] = f2fp8(32.0f * Wp[(size_t)(tk * 64 + r) * 1024 + tn * 64 + c]);
        }
        __syncthreads();
#pragma unroll
        for (int i = 0; i < 16; ++i) {
            int r = r0 + i * 4;
            WTp[(size_t)(tn * 64 + r) * 1024 + tk * 64 + c] = tile[c][r];
        }
    } else {
        // ---- count: per-block expert histogram partials ----
        int b = bx - 18432;                    // 0..127
        if (t < 4) cnt[t] = 0;
        __syncthreads();
        int n = b * 256 + t;
        int lane = t & 63;
        int e = sym[n];
#pragma unroll
        for (int j = 0; j < ENUM; ++j) {
            unsigned long long mask = __ballot(e == j);
            if (mask) {
                int leader = __ffsll((long long)mask) - 1;
                if (lane == leader) atomicAdd(&cnt[j], __popcll(mask));
            }
        }
        __syncthreads();
        if (t < 4) meta[256 + b * 4 + t] = cnt[t];
    }
}

// -- sum partials; write counts/cursors/offs/Mpad; init pad perm slots to 0;
// -- out = constant energy term --
__global__ void k_offsets(int* __restrict__ meta, const float* __restrict__ slope,
                          const float* __restrict__ b3, const float* __restrict__ inter,
                          float* __restrict__ out, int* __restrict__ perm) {
    __shared__ int tot[4], padS[4], padE[4];
    int t = threadIdx.x;
    if (t < 4) {
        int s = 0;
#pragma unroll 8
        for (int b = 0; b < 128; ++b) s += meta[256 + b * 4 + t];
        tot[t] = s;
    }
    __syncthreads();
    if (t == 0) {
        int off = 0;
        float c = 0.f;
        for (int e = 0; e < 4; ++e) {
            int cnt = tot[e];
            meta[e * 16]     = cnt;   // total count
            meta[128 + e]    = off;   // segment start
            meta[64 + e*16]  = off;   // scatter cursor
            padS[e] = off + cnt;      // pad range [padS, padE)
            c += (float)cnt * (slope[e] * b3[e] + inter[e]);
            off += (cnt + 255) & ~255;   // pad to 256
            padE[e] = off;
        }
        meta[132] = off;              // Mpad
        out[0] = c;                   // per-atom constant terms, summed
    }
    __syncthreads();
    // pad perm slots -> row 0, so gemm1's permuted staging reads valid
    // memory (pad rows produce garbage h1, masked by segEnd in FUSE epilogue).
#pragma unroll
    for (int e = 0; e < 4; ++e)
        for (int i = padS[e] + t; i < padE[e]; i += 256) perm[i] = 0;
}

// ---------------- scatter atom ids (wave-aggregated: 4 atomics/wave) ----------------
__global__ void k_scatter(const int* __restrict__ sym, int* __restrict__ meta,
                          int* __restrict__ perm) {
    int n = blockIdx.x * 256 + threadIdx.x;
    int lane = threadIdx.x & 63;
    int e = sym[n];
#pragma unroll
    for (int j = 0; j < ENUM; ++j) {
        unsigned long long mask = __ballot(e == j);
        if (mask) {
            int leader = __ffsll((long long)mask) - 1;
            int base = 0;
            if (lane == leader)
                base = atomicAdd(&meta[64 + j * 16], __popcll(mask));
            base = __shfl(base, leader, 64);
            if (e == j) {
                int rank = __popcll(mask & ((1ull << lane) - 1ull));
                perm[base + rank] = n;
            }
        }
    }
}

// ---------------- MX-fp8 MFMA GEMM: relu(A * (32B)^T * 2^-5 + bias) ----------------
// R14 = R12 verbatim (the 339us-proven structure). Single-buffered LDS,
// __syncthreads 2-barrier K-loop, 256x128 tile, 4 waves of 128x64, 2 blocks/CU.
// Post-mortems R9/R10/R13: every raw-barrier/counted-vmcnt variant regressed
// (377/724/373 vs 339) at every tile size and occupancy tried -- the plain
// __syncthreads loop + implicit multi-block overlap (m114) is the best
// reachable schedule here. Do not re-attempt source-level pipelining.
// (1) FULL bank-conflict-free LDS swizzle: chunk c of row r holds global chunk
//     c ^ (r&7) ^ ((r>>3)&3)  (R12: killed the residual 4-way conflict).
// (2) PERM: gemm1 stages A rows via per-lane PERMUTED global source addresses
//     (global_load_lds global source is per-lane, LDS dest linear -- m173).
// XCD swizzle: grid dim3(8,132) -> 1056 = 132*8 chunked bijective; nt fastest
// per XCD so the 8 blocks sharing an A-panel are co-XCD.
// FUSE=false: store fp8 C.  FUSE=true: fold layer3 dot + slope + global sum.
template <bool FUSE, bool PERM>
__global__ __launch_bounds__(256, 2)
void k_gemm(const u8* __restrict__ A, const u8* __restrict__ BT,
            const float* __restrict__ bias, u8* __restrict__ C,
            const int* __restrict__ meta, const float* __restrict__ W3,
            const float* __restrict__ slope, float* __restrict__ out,
            const int* __restrict__ perm) {
    __shared__ u8 As[256 * 128];   // 32 KB
    __shared__ u8 Bs[128 * 128];   // 16 KB
    const int* offs = meta + 128;

    // grid = dim3(8, 132) -> flat 0..1055; XCD = flat&7 gets contiguous chunk
    const int flat = blockIdx.y * 8 + blockIdx.x;
    const int wgid = (flat & 7) * 132 + (flat >> 3);
    const int mt = wgid >> 3;                  // m tile (0..131), 256 rows
    const int nt = wgid & 7;                   // n tile (0..7), fast index
    const int m0 = mt * 256, n0 = nt * 128;
    if (m0 >= meta[132]) return;               // beyond actual padded M
    const int e = (m0 >= offs[1]) + (m0 >= offs[2]) + (m0 >= offs[3]);

    const int t = threadIdx.x;                 // 0..255
    const int w = t >> 6, lane = t & 63;
    const int l31 = lane & 31, khalf = lane >> 5;
    const int wm = w & 1, wn = w >> 1;         // 2x2 waves, each 128x64

    const u8* Bg = BT + (size_t)e * 1024 * 1024 + (size_t)n0 * 1024;

    // staging: instr i covers rows i*32+(t>>3), 16B chunk t&7; source chunk
    // pre-swizzled (t&7)^(r&7)^((r>>3)&3); LDS linear (global_load_lds rule).
    const int srow = t >> 3;                   // 0..31
    const int gcol = (((t & 7) ^ (srow & 7) ^ ((srow >> 3) & 3)) * 16);

    // per-lane row base pointers (PERM: indirect through perm[], pads -> row 0)
    const u8* arow[8];
#pragma unroll
    for (int i = 0; i < 8; ++i) {
        int r = i * 32 + srow;
        size_t src = PERM ? (size_t)perm[m0 + r] : (size_t)(m0 + r);
        arow[i] = A + src * 1024 + gcol;
    }
    const u8* brow[4];
#pragma unroll
    for (int i = 0; i < 4; ++i)
        brow[i] = Bg + (size_t)(i * 32 + srow) * 1024 + gcol;

    f32x16 acc[4][2] = {};

    for (int kt = 0; kt < 1024 / 128; ++kt) {
        const int kb = kt * 128;
#pragma unroll
        for (int i = 0; i < 8; ++i)            // A: 256 rows, 8 instrs
            __builtin_amdgcn_global_load_lds((const void*)(arow[i] + kb),
                (void*)(As + i * 4096 + w * 1024), 16, 0, 0);
#pragma unroll
        for (int i = 0; i < 4; ++i)            // B: 128 rows, 4 instrs
            __builtin_amdgcn_global_load_lds((const void*)(brow[i] + kb),
                (void*)(Bs + i * 4096 + w * 1024), 16, 0, 0);
        __syncthreads();

#pragma unroll
        for (int kk = 0; kk < 2; ++kk) {
            const int c0 = 4 * kk + 2 * khalf;    // even
            i32x8 b[2];
#pragma unroll
            for (int ni = 0; ni < 2; ++ni) {
                int n = wn * 64 + ni * 32 + l31;
                const u8* base = Bs + n * 128;
                int sw = (n & 7) ^ ((n >> 3) & 3);
                int lo = ((c0 ^ sw) << 4);
                union { uint4 q[2]; i32x8 v; } u;
                u.q[0] = *(const uint4*)(const void*)(base + lo);
                u.q[1] = *(const uint4*)(const void*)(base + (lo ^ 16));
                b[ni] = u.v;
            }
#pragma unroll
            for (int mi = 0; mi < 4; ++mi) {
                int m = wm * 128 + mi * 32 + l31;
                const u8* base = As + m * 128;
                int sw = (m & 7) ^ ((m >> 3) & 3);
                int lo = ((c0 ^ sw) << 4);
                union { uint4 q[2]; i32x8 v; } u;
                u.q[0] = *(const uint4*)(const void*)(base + lo);
                u.q[1] = *(const uint4*)(const void*)(base + (lo ^ 16));
                i32x8 a = u.v;
#pragma unroll
                for (int ni = 0; ni < 2; ++ni)
                    acc[mi][ni] = __builtin_amdgcn_mfma_scale_f32_32x32x64_f8f6f4(
                        a, b[ni], acc[mi][ni],
                        0, 0,                       // cbsz=fp8(e4m3), blgp=fp8(e4m3)
                        0, 0x7F7F7F7F,              // A scale 2^0
                        0, 0x7A7A7A7A);             // B scale 2^-5 (undo 32*W)
            }
        }
        __syncthreads();
    }

    // epilogue.  32x32 C/D layout: col=lane&31, row=(reg&3)+8*(reg>>2)+4*(lane>>5)
    if (!FUSE) {
#pragma unroll
        for (int ni = 0; ni < 2; ++ni) {
            int col = n0 + wn * 64 + ni * 32 + l31;
            float bv = bias[e * 1024 + col];
#pragma unroll
            for (int mi = 0; mi < 4; ++mi) {
                int rowb = m0 + wm * 128 + mi * 32 + 4 * khalf;
#pragma unroll
                for (int reg = 0; reg < 16; ++reg) {
                    int rowg = rowb + (reg & 3) + 8 * (reg >> 2);
                    float v = acc[mi][ni][reg] + bv;
                    v = v > 0.f ? v : 0.f;
                    C[(size_t)rowg * 1024 + col] = f2fp8(v);
                }
            }
        }
    } else {
        const int segEnd = offs[e] + meta[e * 16];   // valid slots < segEnd
        const float se = slope[e];
        float psum = 0.f;
#pragma unroll
        for (int ni = 0; ni < 2; ++ni) {
            int col = n0 + wn * 64 + ni * 32 + l31;
            float bv  = bias[e * 1024 + col];
            float w3s = W3[e * 1024 + col] * se;
#pragma unroll
            for (int mi = 0; mi < 4; ++mi) {
                int rowb = m0 + wm * 128 + mi * 32 + 4 * khalf;
#pragma unroll
                for (int reg = 0; reg < 16; ++reg) {
                    int rowg = rowb + (reg & 3) + 8 * (reg >> 2);
                    float v = acc[mi][ni][reg] + bv;
                    v = v > 0.f ? v : 0.f;
                    psum += (rowg < segEnd) ? v * w3s : 0.f;
                }
            }
        }
#pragma unroll
        for (int o = 32; o; o >>= 1) psum += __shfl_xor(psum, o, 64);
        float* red = (float*)As;    // safe: all LDS reads done (loop-final barrier)
        if (lane == 0) red[w] = psum;
        __syncthreads();
        if (t == 0) atomicAdd(out, red[0] + red[1] + red[2] + red[3]);
    }
}

extern "C" void kernel_launch(void* const* d_in, const int* in_sizes, int n_in,
                              void* d_out, int out_size, void* d_ws, size_t ws_size,
                              hipStream_t stream) {
    const float* features = (const float*)d_in[0];
    const int*   sym      = (const int*)d_in[1];
    const float* W1       = (const float*)d_in[2];
    const float* b1       = (const float*)d_in[3];
    const float* W2       = (const float*)d_in[4];
    const float* b2       = (const float*)d_in[5];
    const float* W3       = (const float*)d_in[6];
    const float* b3       = (const float*)d_in[7];
    const float* slope    = (const float*)d_in[8];
    const float* inter    = (const float*)d_in[9];
    float* out = (float*)d_out;

    char* ws  = (char*)d_ws;
    u8*  X8   = (u8*)(ws + XP_OFF);
    u8*  H1b  = (u8*)(ws + H1_OFF);
    u8*  W1T  = (u8*)(ws + W1T_OFF);
    u8*  W2T  = (u8*)(ws + W2T_OFF);
    int* perm = (int*)(ws + PERM_OFF);
    int* meta = (int*)(ws + META_OFF);

    // conv8 (16384 blocks) | transw (2048) | count (128) fused: one launch
    k_fused<<<16384 + 2048 + 128, 256, 0, stream>>>(features, X8, W1, W1T,
                                                    W2, W2T, sym, meta);
    k_offsets<<<1, 256, 0, stream>>>(meta, slope, b3, inter, out, perm);
    k_scatter<<<NATOMS / 256, 256, 0, stream>>>(sym, meta, perm);
    k_gemm<false, true><<<dim3(8, 132), 256, 0, stream>>>(X8, W1T, b1, H1b, meta,
                                                          nullptr, nullptr, nullptr,
                                                          perm);
    k_gemm<true, false><<<dim3(8, 132), 256, 0, stream>>>(H1b, W2T, b2, nullptr,
                                                          meta, W3, slope, out,
                                                          nullptr);
}